// Round 8
// baseline (2544.569 us; speedup 1.0000x reference)
//
#include <hip/hip_runtime.h>

typedef unsigned short ushort;
typedef unsigned int uint;
typedef __bf16 bf16_t;
typedef bf16_t bf16x8 __attribute__((ext_vector_type(8)));
typedef float f32x4 __attribute__((ext_vector_type(4)));

#define B_ 2048
#define T_ 512
#define D_ 5
#define H_ 128
#define C_ 10
#define BT 8        // batch rows per block (grid = 256 = one block per CU)
#define BLK 512     // 8 waves, 2 waves/SIMD
#define HSTR 136    // h tile row stride in ushorts (8 live rows, 16B-aligned)

// ---- static-LDS layout (ushort offsets) ----
#define A0O  0                  // h0 bufs x4 (pairs): 4 x 8 x HSTR = 4352
#define B1EO (A0O + 4352)       // h1 even-step buf: 1088
#define B1OO (B1EO + 1088)      // h1 odd-step buf: 1088
#define ZRO  (B1OO + 1088)      // zero row: 136 (masked A-frag rows land here)
#define XCO  (ZRO + 136)        // x ring: 16 slots x 8 rows x 8 ush + 32 pad = 1056
#define LDSU (XCO + 1056)       // 7720 ush = 15440 B

static __device__ __forceinline__ float b2f(ushort u) {
    return __builtin_bit_cast(float, ((uint)u) << 16);
}
static __device__ __forceinline__ ushort f2b(float f) {
    uint u = __builtin_bit_cast(uint, f);
    u += 0x7FFFu + ((u >> 16) & 1u);   // RNE
    return (ushort)(u >> 16);
}
// inf-safe: exp->inf => rcp->0 => sigmoid->0/1, tanh->+-1
static __device__ __forceinline__ float sigf(float x) {
    return __builtin_amdgcn_rcpf(1.0f + __expf(-x));
}
static __device__ __forceinline__ float tanhf_(float x) {
    return 1.0f - 2.0f * __builtin_amdgcn_rcpf(1.0f + __expf(2.0f * x));
}
static __device__ __forceinline__ float ldf(const void* p, long i, bool m32) {
    return m32 ? ((const float*)p)[i] : b2f(((const ushort*)p)[i]);
}
static __device__ __forceinline__ bf16x8 ld16(const ushort* p) {
    return __builtin_bit_cast(bf16x8, *(const uint4*)p);
}
static __device__ __forceinline__ bf16x8 ldfrag(const void* p, long idx, bool m32) {
    if (!m32) return ld16((const ushort*)p + idx);
    const float* f = (const float*)p + idx;
    union { ushort u[8]; bf16x8 v; } r;
#pragma unroll
    for (int j = 0; j < 8; ++j) r.u[j] = f2b(f[j]);
    return r.v;
}
static __device__ __forceinline__ f32x4 splat4(float v) {
    f32x4 r = {v, v, v, v};
    return r;
}
// lgkm-only barrier: LDS exchange without draining global loads in flight
static __device__ __forceinline__ void bar_lds() {
    asm volatile("s_waitcnt lgkmcnt(0)" ::: "memory");
    __builtin_amdgcn_s_barrier();
    asm volatile("" ::: "memory");
}

// ---- dtype detector (proven; picks f32 vs bf16)
__global__ void detect_dtype(const ushort* __restrict__ w, int* __restrict__ flag) {
    __shared__ int cnt;
    if (threadIdx.x == 0) cnt = 0;
    __syncthreads();
    int local = 0;
    for (int i = threadIdx.x; i < 16384; i += 256)
        if ((uint)(w[i] & 0x7F80u) >= 0x4180u) ++local;   // |v| >= 16
    atomicAdd(&cnt, local);
    __syncthreads();
    if (threadIdx.x == 0) *flag = (cnt > 512) ? 1 : 0;
}

// =====================================================================
// Fully-fused two-layer LSTM, 256 blocks (1/CU), 8 rows/block, 8 waves.
// 2-step batched iteration: L0 computes steps {2I, 2I+1}; L1 lags by 2
// and computes steps {2I-2, 2I-1} (batched ih-GEMM consumes only h0
// values that already exist: rows 0-7 = h0(2I-2), rows 8-15 = h0(2I-1)).
// R8: ALL THREE weight matrices in registers (each wave covers 64 N-cols
// of each -> 64 VGPR/matrix). No wi1 LDS reads; LDS shrinks to 15 KB.
//   - recurrent hh-GEMMs per phase with zero-masked A-frags.
//   - cell state alternates quad pairs, handed across __shfl_xor(c,32).
//   - 2 lgkm-only barriers per 2 steps. Final iteration I=256 is L1-only.
// =====================================================================
__global__ __launch_bounds__(BLK, 2) void lstm2_fr(
    const void* __restrict__ x,
    const void* __restrict__ wih0, const void* __restrict__ whh0,
    const void* __restrict__ bih0, const void* __restrict__ bhh0,
    const void* __restrict__ wih1, const void* __restrict__ whh1,
    const void* __restrict__ bih1, const void* __restrict__ bhh1,
    const void* __restrict__ cw1, const void* __restrict__ cb1,
    const void* __restrict__ cw2, const void* __restrict__ cb2,
    const int* __restrict__ flag, void* __restrict__ out)
{
    __shared__ __align__(16) ushort lds[LDSU];

    const bool m32 = (*flag) != 0;
    const int tid  = threadIdx.x;
    const int w    = tid >> 6;
    const int lane = tid & 63;
    const int quad = lane >> 4;
    const int l16  = lane & 15;
    const int r8   = l16 & 7;
    const bool lo8 = (l16 < 8);
    const int bt0  = blockIdx.x * BT;

    // zero: h0 pair 1 (read at I=0 as h0(-2)/h0(-1)); h1 bufs; ZRO + x ring
    for (int i = tid; i < 2176; i += BLK) {
        lds[A0O + 2176 + i] = 0;
        lds[B1EO + i] = 0;
    }
    for (int i = tid; i < 136 + 1056; i += BLK) lds[ZRO + i] = 0;

    // ---- weights: whh0 / whh1 / wih1 ALL in registers; wih0 (K-padded) regs
    bf16x8 wh0[4][4], wh1[4][4], wi1[4][4], xw[4];
    float  b0[4], b1v[4];
#pragma unroll
    for (int g = 0; g < 4; ++g) {
        const int n = g * 128 + w * 16 + l16;
#pragma unroll
        for (int kt = 0; kt < 4; ++kt) {
            wh0[g][kt] = ldfrag(whh0, (long)n * 128 + kt * 32 + quad * 8, m32);
            wh1[g][kt] = ldfrag(whh1, (long)n * 128 + kt * 32 + quad * 8, m32);
            wi1[g][kt] = ldfrag(wih1, (long)n * 128 + kt * 32 + quad * 8, m32);
        }
        union { ushort u[8]; bf16x8 v; } xt;
#pragma unroll
        for (int j = 0; j < 8; ++j) xt.u[j] = 0;
        if (quad == 0) {
#pragma unroll
            for (int j = 0; j < 5; ++j) xt.u[j] = f2b(ldf(wih0, (long)n * D_ + j, m32));
        }
        xw[g] = xt.v;
        b0[g]  = ldf(bih0, n, m32) + ldf(bhh0, n, m32);
        b1v[g] = ldf(bih1, n, m32) + ldf(bhh1, n, m32);
    }

    // ---- x staging: chunk = 8 steps x 8 rows x 5 = 320 elems; slot = 64 ush
    const bool xact = tid < 320;
    const int  e    = xact ? tid : 0;
    const int  rr   = e / 40, rem = e - rr * 40;
    const int  tt   = rem / 5, dd = rem - tt * 5;
    const long xo   = (long)(bt0 + rr) * T_ * D_ + (long)tt * D_ + dd;
    const int  xd   = tt * 64 + rr * 8 + dd;
    if (xact) {
        lds[XCO + xd]       = f2b(ldf(x, xo, m32));            // steps 0-7
        lds[XCO + 512 + xd] = f2b(ldf(x, xo + 8 * D_, m32));   // steps 8-15
    }
    float xp = xact ? ldf(x, xo + 16 * D_, m32) : 0.f;         // steps 16-23
    __syncthreads();

    f32x4 c0 = splat4(0.f), c1 = splat4(0.f);

    // invariant masked h1 A-frag row bases (L1 lag-2 schedule):
    //   even phase (step 2I-2) hh input = h1(2I-3) -> odd buffer, rows 0-7
    //   odd  phase (step 2I-1) hh input = h1(2I-2) -> even buffer, rows 8-15
    const ushort* pH1e = lds + (lo8 ? B1OO + r8 * HSTR : ZRO);
    const ushort* pH1o = lds + (lo8 ? ZRO : B1EO + r8 * HSTR);

#pragma unroll 1
    for (int I = 0; I <= 256; ++I) {
        // x chunk boundary (every 4 iters = 8 steps): write staged chunk, prefetch next
        if ((I & 3) == 0 && I > 0 && I < 256) {
            if (xact) {
                lds[XCO + ((2 * I + 8) & 15) * 64 + xd] = f2b(xp);
                const int S = 2 * I + 16;
                xp = (S + tt < T_) ? ldf(x, xo + (long)S * D_, m32) : 0.f;
            }
        }
        const int s = I & 1;
        const int bIhLo = A0O + (s ^ 1) * 2176;        // h0(2I-2)
        const int bIhHi = bIhLo + 1088;                // h0(2I-1)
        const int bWr0  = A0O + s * 2176;              // h0(2I) write
        const int bWr1  = bWr0 + 1088;                 // h0(2I+1) write
        const ushort* pIh  = lds + (lo8 ? bIhLo + r8 * HSTR : bIhHi + r8 * HSTR);
        const ushort* pH0e = lds + (lo8 ? bIhHi + r8 * HSTR : ZRO);
        const ushort* pH0o = lds + (lo8 ? ZRO : bWr0 + r8 * HSTR);
        const ushort* pXa  = lds + XCO + ((2 * I) & 15) * 64 + l16 * 8 + quad * 8;

        // ===== batched pre-GEMMs: ih1 (reg B-operands, starts right after
        //       the 4 pIh reads) + x (L0 both steps) =====
        f32x4 a0[4], a1[4];
#pragma unroll
        for (int g = 0; g < 4; ++g) { a0[g] = splat4(b0[g]); a1[g] = splat4(b1v[g]); }
#pragma unroll
        for (int kt = 0; kt < 4; ++kt) {
            bf16x8 ha = ld16(pIh + kt * 32 + quad * 8);
#pragma unroll
            for (int g = 0; g < 4; ++g)
                a1[g] = __builtin_amdgcn_mfma_f32_16x16x32_bf16(
                    ha, wi1[g][kt], a1[g], 0, 0, 0);
        }
        {
            bf16x8 xaf = ld16(pXa);   // k>=5 junk x zero-weight = 0
#pragma unroll
            for (int g = 0; g < 4; ++g)
                a0[g] = __builtin_amdgcn_mfma_f32_16x16x32_bf16(
                    xaf, xw[g], a0[g], 0, 0, 0);
        }
        // ===== even-phase hh (C rows 0-7; rows 8-15 add exact zero) =====
#pragma unroll
        for (int kt = 0; kt < 4; ++kt) {
            bf16x8 he = ld16(pH0e + kt * 32 + quad * 8);
#pragma unroll
            for (int g = 0; g < 4; ++g)
                a0[g] = __builtin_amdgcn_mfma_f32_16x16x32_bf16(
                    he, wh0[g][kt], a0[g], 0, 0, 0);
        }
#pragma unroll
        for (int kt = 0; kt < 4; ++kt) {
            bf16x8 h1e = ld16(pH1e + kt * 32 + quad * 8);
#pragma unroll
            for (int g = 0; g < 4; ++g)
                a1[g] = __builtin_amdgcn_mfma_f32_16x16x32_bf16(
                    h1e, wh1[g][kt], a1[g], 0, 0, 0);
        }
        // ===== even acts =====
        if (I < 256) {   // L0 step 2I -> h0(2I)  (quads 0,1 hold valid rows)
            f32x4 cp;
#pragma unroll
            for (int r = 0; r < 4; ++r) cp[r] = __shfl_xor(c0[r], 32);
#pragma unroll
            for (int r = 0; r < 4; ++r) {
                float iv = sigf(a0[0][r]), fv = sigf(a0[1][r]);
                float gv = tanhf_(a0[2][r]), ov = sigf(a0[3][r]);
                float cv = fv * cp[r] + iv * gv;
                c0[r] = cv;
                ushort hv = f2b(ov * tanhf_(cv));
                if (quad < 2)
                    lds[bWr0 + (quad * 4 + r) * HSTR + w * 16 + l16] = hv;
            }
        }
        if (I > 0) {     // L1 step 2I-2 -> h1(2I-2) into EVEN buffer
            f32x4 cq;
#pragma unroll
            for (int r = 0; r < 4; ++r) cq[r] = __shfl_xor(c1[r], 32);
#pragma unroll
            for (int r = 0; r < 4; ++r) {
                float iv = sigf(a1[0][r]), fv = sigf(a1[1][r]);
                float gv = tanhf_(a1[2][r]), ov = sigf(a1[3][r]);
                float cv = fv * cq[r] + iv * gv;
                c1[r] = cv;
                ushort hv = f2b(ov * tanhf_(cv));
                if (quad < 2)
                    lds[B1EO + (quad * 4 + r) * HSTR + w * 16 + l16] = hv;
            }
        }
        bar_lds();   // mid barrier: h0(2I), h1(2I-2) visible

        // ===== odd-phase hh (C rows 8-15; rows 0-7 add exact zero) =====
#pragma unroll
        for (int kt = 0; kt < 4; ++kt) {
            bf16x8 ho = ld16(pH0o + kt * 32 + quad * 8);
#pragma unroll
            for (int g = 0; g < 4; ++g)
                a0[g] = __builtin_amdgcn_mfma_f32_16x16x32_bf16(
                    ho, wh0[g][kt], a0[g], 0, 0, 0);
        }
#pragma unroll
        for (int kt = 0; kt < 4; ++kt) {
            bf16x8 h1o = ld16(pH1o + kt * 32 + quad * 8);
#pragma unroll
            for (int g = 0; g < 4; ++g)
                a1[g] = __builtin_amdgcn_mfma_f32_16x16x32_bf16(
                    h1o, wh1[g][kt], a1[g], 0, 0, 0);
        }
        // ===== odd acts (quads 2,3 hold valid rows 8-15) =====
        if (I < 256) {   // L0 step 2I+1 -> h0(2I+1)
            f32x4 cp;
#pragma unroll
            for (int r = 0; r < 4; ++r) cp[r] = __shfl_xor(c0[r], 32);
#pragma unroll
            for (int r = 0; r < 4; ++r) {
                float iv = sigf(a0[0][r]), fv = sigf(a0[1][r]);
                float gv = tanhf_(a0[2][r]), ov = sigf(a0[3][r]);
                float cv = fv * cp[r] + iv * gv;
                c0[r] = cv;
                ushort hv = f2b(ov * tanhf_(cv));
                if (quad >= 2)
                    lds[bWr1 + ((quad - 2) * 4 + r) * HSTR + w * 16 + l16] = hv;
            }
        }
        if (I > 0) {     // L1 step 2I-1 -> h1(2I-1) into ODD buffer
            f32x4 cq;
#pragma unroll
            for (int r = 0; r < 4; ++r) cq[r] = __shfl_xor(c1[r], 32);
#pragma unroll
            for (int r = 0; r < 4; ++r) {
                float iv = sigf(a1[0][r]), fv = sigf(a1[1][r]);
                float gv = tanhf_(a1[2][r]), ov = sigf(a1[3][r]);
                float cv = fv * cq[r] + iv * gv;
                c1[r] = cv;
                ushort hv = f2b(ov * tanhf_(cv));
                if (quad >= 2)
                    lds[B1OO + ((quad - 2) * 4 + r) * HSTR + w * 16 + l16] = hv;
            }
        }
        bar_lds();   // end barrier
    }
    __syncthreads();

    // ---------- classifier + outputs (h1(511) in B1OO rows 0-7) ----------
    float* rs = (float*)&lds[XCO];   // x ring dead; reuse as [8][64] f32 (needs 2048B > 1056*2? no: 8*64*4 = 2048B = 1024 ush -> fits in 1056)
    if (tid < 128) {
        int m = tid >> 4, j0 = (tid & 15) * 4;
        float s0 = ldf(cb1, j0, m32), s1 = ldf(cb1, j0 + 1, m32);
        float s2 = ldf(cb1, j0 + 2, m32), s3 = ldf(cb1, j0 + 3, m32);
        const ushort* hr = &lds[B1OO + m * HSTR];
#pragma unroll 4
        for (int k = 0; k < 128; ++k) {
            float hv = b2f(hr[k]);
            s0 += hv * ldf(cw1, (long)j0 * 128 + k, m32);
            s1 += hv * ldf(cw1, (long)(j0 + 1) * 128 + k, m32);
            s2 += hv * ldf(cw1, (long)(j0 + 2) * 128 + k, m32);
            s3 += hv * ldf(cw1, (long)(j0 + 3) * 128 + k, m32);
        }
        rs[m * 64 + j0]     = fmaxf(s0, 0.f);
        rs[m * 64 + j0 + 1] = fmaxf(s1, 0.f);
        rs[m * 64 + j0 + 2] = fmaxf(s2, 0.f);
        rs[m * 64 + j0 + 3] = fmaxf(s3, 0.f);
    }
    __syncthreads();
    if (tid < 80) {
        int m = tid / 10, cc = tid - m * 10;
        float s = ldf(cb2, cc, m32);
#pragma unroll
        for (int j = 0; j < 64; ++j)
            s += rs[m * 64 + j] * ldf(cw2, (long)cc * 64 + j, m32);
        long oi = (long)(bt0 + m) * C_ + cc;
        if (m32) ((float*)out)[oi] = s; else ((ushort*)out)[oi] = f2b(s);
    }
    for (int idx = tid; idx < BT * H_; idx += BLK) {
        int m = idx >> 7, k = idx & 127;
        float v = b2f(lds[B1OO + m * HSTR + k]);
        long oi = (long)B_ * C_ + (long)(bt0 + m) * H_ + k;
        if (m32) ((float*)out)[oi] = v; else ((ushort*)out)[oi] = f2b(v);
    }
}

extern "C" void kernel_launch(void* const* d_in, const int* in_sizes, int n_in,
                              void* d_out, int out_size, void* d_ws, size_t ws_size,
                              hipStream_t stream) {
    (void)in_sizes; (void)n_in; (void)out_size; (void)ws_size;
    int* flag = (int*)d_ws;

    hipLaunchKernelGGL(detect_dtype, dim3(1), dim3(256), 0, stream,
                       (const ushort*)d_in[2], flag);

    hipLaunchKernelGGL(lstm2_fr, dim3(B_ / BT), dim3(BLK), 0, stream,
                       d_in[0], d_in[1], d_in[2], d_in[3], d_in[4],
                       d_in[5], d_in[6], d_in[7], d_in[8],
                       d_in[9], d_in[10], d_in[11], d_in[12],
                       (const int*)flag, d_out);
}

// Round 9
// 905.768 us; speedup vs baseline: 2.8093x; 2.8093x over previous
//
#include <hip/hip_runtime.h>

typedef unsigned short ushort;
typedef unsigned int uint;
typedef __bf16 bf16_t;
typedef bf16_t bf16x8 __attribute__((ext_vector_type(8)));
typedef float f32x4 __attribute__((ext_vector_type(4)));

#define B_ 2048
#define T_ 512
#define D_ 5
#define H_ 128
#define C_ 10
#define BT 16      // batch tile per workgroup
#define BLK 512    // 8 waves, 2 waves/SIMD
#define NP 128     // producer/consumer pair count
#define CH 8       // pipeline chunk (steps per sync)
#define H0STR 168  // LDS row stride in ushorts (h0 row 128 + x cols + pad)
#define H1STR 136  // h1 row stride (128 + 8 pad)

static __device__ __forceinline__ float b2f(ushort u) {
    return __builtin_bit_cast(float, ((uint)u) << 16);
}
static __device__ __forceinline__ ushort f2b(float f) {
    uint u = __builtin_bit_cast(uint, f);
    u += 0x7FFFu + ((u >> 16) & 1u);   // RNE
    return (ushort)(u >> 16);
}
// inf-safe: exp->inf => rcp->0 => sigmoid->0/1, tanh->+-1
static __device__ __forceinline__ float sigf(float x) {
    return __builtin_amdgcn_rcpf(1.0f + __expf(-x));
}
static __device__ __forceinline__ float tanhf_(float x) {
    return 1.0f - 2.0f * __builtin_amdgcn_rcpf(1.0f + __expf(2.0f * x));
}
static __device__ __forceinline__ float ldf(const void* p, long i, bool m32) {
    return m32 ? ((const float*)p)[i] : b2f(((const ushort*)p)[i]);
}
static __device__ __forceinline__ bf16x8 ld16(const ushort* p) {
    return __builtin_bit_cast(bf16x8, *(const uint4*)p);
}
static __device__ __forceinline__ bf16x8 ldfrag(const void* p, long idx, bool m32) {
    if (!m32) return ld16((const ushort*)p + idx);
    const float* f = (const float*)p + idx;
    union { ushort u[8]; bf16x8 v; } r;
#pragma unroll
    for (int j = 0; j < 8; ++j) r.u[j] = f2b(f[j]);
    return r.v;
}
static __device__ __forceinline__ f32x4 splat4(float v) {
    f32x4 r = {v, v, v, v};
    return r;
}

// ---- dtype detector (proven R2-R5; picks f32)
__global__ void detect_dtype(const ushort* __restrict__ w, int* __restrict__ flag) {
    __shared__ int cnt;
    if (threadIdx.x == 0) cnt = 0;
    __syncthreads();
    int local = 0;
    for (int i = threadIdx.x; i < 16384; i += 256)
        if ((uint)(w[i] & 0x7F80u) >= 0x4180u) ++local;   // |v| >= 16
    atomicAdd(&cnt, local);
    __syncthreads();
    if (threadIdx.x == 0) *flag = (cnt > 512) ? 1 : 0;
}

// ---- zero the pipeline progress flags (d_ws is poisoned before each launch)
__global__ void init_flags(int* __restrict__ prog) {
    prog[threadIdx.x] = 0;   // 256 ints: prog_p[128], prog_c[128]
}

// =====================================================================
// Pipelined kernel: block p<NP = layer-0 producer; block NP+p = layer-1
// consumer + classifier. h0 streamed via ring FIFO (F slots) in d_ws.
// =====================================================================
__global__ __launch_bounds__(BLK, 2) void lstm2_pipe(
    const void* __restrict__ x,
    const void* __restrict__ wih0, const void* __restrict__ whh0,
    const void* __restrict__ bih0, const void* __restrict__ bhh0,
    const void* __restrict__ wih1, const void* __restrict__ whh1,
    const void* __restrict__ bih1, const void* __restrict__ bhh1,
    const void* __restrict__ cw1, const void* __restrict__ cb1,
    const void* __restrict__ cw2, const void* __restrict__ cb2,
    const int* __restrict__ flag,
    ushort* __restrict__ fifo, int* __restrict__ prog_p, int* __restrict__ prog_c,
    int F, void* __restrict__ out)
{
    __shared__ __align__(16) ushort sA[2][BT * H0STR]; // prod: h0+x; cons: staged h0
    __shared__ __align__(16) ushort sB[2][BT * H1STR]; // cons: h1 recurrence
    __shared__ float rs[BT * 64];                      // cons: classifier hidden

    const bool m32 = (*flag) != 0;
    const int tid  = threadIdx.x;
    const int w    = tid >> 6;
    const int lane = tid & 63;
    const int quad = lane >> 4;
    const int l16  = lane & 15;

    if ((int)blockIdx.x < NP) {
        // ================= PRODUCER: layer 0 =================
        const int p   = blockIdx.x;
        const int bt0 = p * BT;
        ushort* myfifo = fifo + (long)p * F * (BT * H_);

        // stage x(0) into sA[0] cols 128..159; zeros into sA[1]
        for (int i = tid; i < BT * 32; i += BLK) {
            int row = i >> 5, cc = i & 31;
            ushort v0 = (cc < 5) ? f2b(ldf(x, ((long)(bt0 + row) * T_) * D_ + cc, m32))
                                 : (ushort)0;
            sA[0][row * H0STR + 128 + cc] = v0;
            sA[1][row * H0STR + 128 + cc] = 0;
        }

        // weights: w_hh0 frags + x-tile frags (registers; ~150 regs/wave total)
        bf16x8 wh0c[4][4];
        bf16x8 xbf[4];
        float  b0v[4];
#pragma unroll
        for (int g = 0; g < 4; ++g) {
            const int n = g * 128 + w * 16 + l16;
#pragma unroll
            for (int kt = 0; kt < 4; ++kt)
                wh0c[g][kt] = ldfrag(whh0, (long)n * 128 + kt * 32 + quad * 8, m32);
            union { ushort u[8]; bf16x8 v; } xt;
#pragma unroll
            for (int j = 0; j < 8; ++j) xt.u[j] = 0;
            if (quad == 0) {
#pragma unroll
                for (int j = 0; j < 5; ++j) xt.u[j] = f2b(ldf(wih0, (long)n * D_ + j, m32));
            }
            xbf[g] = xt.v;
            b0v[g] = ldf(bih0, n, m32) + ldf(bhh0, n, m32);
        }
        __syncthreads();

        bf16x8 h0f[4];
        {
            uint4 z = make_uint4(0, 0, 0, 0);
            h0f[0] = h0f[1] = h0f[2] = h0f[3] = __builtin_bit_cast(bf16x8, z);
        }
        f32x4 c0 = splat4(0.f);
        const int xr = tid / 5, xc = tid - (tid / 5) * 5;

#pragma unroll 1
        for (int t = 0; t < T_; ++t) {
            const int rb = t & 1, wb = (t + 1) & 1;
            if ((t & (CH - 1)) == 0 && t > 0) {
                if (tid == 0) {
                    // publish steps < t (all FIFO stores drained by prior barrier)
                    __hip_atomic_store(&prog_p[p], t, __ATOMIC_RELEASE,
                                       __HIP_MEMORY_SCOPE_AGENT);
                    int need = t + CH - F;   // ring WAR throttle
                    if (need > 0)
                        while (__hip_atomic_load(&prog_c[p], __ATOMIC_ACQUIRE,
                                                 __HIP_MEMORY_SCOPE_AGENT) < need)
                            __builtin_amdgcn_s_sleep(2);
                }
                __syncthreads();
            }
            float xv = 0.f;
            const bool stage = (tid < 80) && (t < T_ - 1);
            if (stage) xv = ldf(x, ((long)(bt0 + xr) * T_ + (t + 1)) * D_ + xc, m32);

            f32x4 a[4];
#pragma unroll
            for (int g = 0; g < 4; ++g) a[g] = splat4(b0v[g]);
#pragma unroll
            for (int kt = 0; kt < 4; ++kt)
#pragma unroll
                for (int g = 0; g < 4; ++g)
                    a[g] = __builtin_amdgcn_mfma_f32_16x16x32_bf16(
                        h0f[kt], wh0c[g][kt], a[g], 0, 0, 0);
            {
                bf16x8 ha4 = ld16(&sA[rb][l16 * H0STR + 128 + quad * 8]);
#pragma unroll
                for (int g = 0; g < 4; ++g)
                    a[g] = __builtin_amdgcn_mfma_f32_16x16x32_bf16(
                        ha4, xbf[g], a[g], 0, 0, 0);
            }
            ushort* fs = myfifo + (long)(t & (F - 1)) * (BT * H_);
#pragma unroll
            for (int r = 0; r < 4; ++r) {
                float iv = sigf(a[0][r]), fv = sigf(a[1][r]);
                float gv = tanhf_(a[2][r]), ov = sigf(a[3][r]);
                float cv = fv * c0[r] + iv * gv;
                c0[r] = cv;
                ushort hv = f2b(ov * tanhf_(cv));
                int row = quad * 4 + r;
                sA[wb][row * H0STR + w * 16 + l16] = hv;
                fs[row * H_ + w * 16 + l16] = hv;       // FIFO (pre-barrier)
            }
            if (stage) sA[wb][xr * H0STR + 128 + xc] = f2b(xv);
            __syncthreads();
#pragma unroll
            for (int kt = 0; kt < 4; ++kt)
                h0f[kt] = ld16(&sA[wb][l16 * H0STR + kt * 32 + quad * 8]);
        }
        if (tid == 0)
            __hip_atomic_store(&prog_p[p], T_, __ATOMIC_RELEASE,
                               __HIP_MEMORY_SCOPE_AGENT);
    } else {
        // ================= CONSUMER: layer 1 + classifier =================
        const int p   = blockIdx.x - NP;
        const int bt0 = p * BT;
        const ushort* myfifo = fifo + (long)p * F * (BT * H_);

        // zero h1(-1)
        for (int i = tid; i < BT * H_; i += BLK) {
            int row = i >> 7, cc = i & 127;
            sB[0][row * H1STR + cc] = 0;
        }

        // weights: w_ih1 + w_hh1 frags (~190 regs/wave total)
        bf16x8 wi1f[4][4], wh1f[4][4];
        float  b1v[4];
#pragma unroll
        for (int g = 0; g < 4; ++g) {
            const int n = g * 128 + w * 16 + l16;
#pragma unroll
            for (int kt = 0; kt < 4; ++kt) {
                wi1f[g][kt] = ldfrag(wih1, (long)n * 128 + kt * 32 + quad * 8, m32);
                wh1f[g][kt] = ldfrag(wih1 == whh1 ? whh1 : whh1,
                                     (long)n * 128 + kt * 32 + quad * 8, m32);
            }
            b1v[g] = ldf(bih1, n, m32) + ldf(bhh1, n, m32);
        }

        // wait for first two chunks, then stage h0(0)
        if (tid == 0) {
            while (__hip_atomic_load(&prog_p[p], __ATOMIC_ACQUIRE,
                                     __HIP_MEMORY_SCOPE_AGENT) < 2 * CH)
                __builtin_amdgcn_s_sleep(2);
        }
        __syncthreads();
        {
            int row = tid >> 5, col4 = (tid & 31) * 4;
            uint2 d = *(const uint2*)(myfifo + tid * 4);
            *(uint2*)&sA[0][row * H0STR + col4] = d;
        }
        __syncthreads();

        f32x4 c1 = splat4(0.f);

#pragma unroll 1
        for (int t = 0; t < T_; ++t) {
            const int rb = t & 1, wb = (t + 1) & 1;
            // chunk boundary BEFORE prefetching into the next chunk:
            // acquire-invalidate precedes every read of newly-ready slots.
            if (((t + 1) & (CH - 1)) == 0 && t + 1 < T_) {
                if (tid == 0) {
                    int target = t + 1 + CH;
                    if (target > T_) target = T_;
                    while (__hip_atomic_load(&prog_p[p], __ATOMIC_ACQUIRE,
                                             __HIP_MEMORY_SCOPE_AGENT) < target)
                        __builtin_amdgcn_s_sleep(2);
                    __hip_atomic_store(&prog_c[p], t + 1, __ATOMIC_RELEASE,
                                       __HIP_MEMORY_SCOPE_AGENT);
                }
                __syncthreads();
            }
            // prefetch h0(t+1)
            uint2 pf = make_uint2(0, 0);
            const bool hn = (t + 1 < T_);
            if (hn) pf = *(const uint2*)(myfifo
                          + (long)((t + 1) & (F - 1)) * (BT * H_) + tid * 4);

            f32x4 a[4];
#pragma unroll
            for (int g = 0; g < 4; ++g) a[g] = splat4(b1v[g]);
#pragma unroll
            for (int kt = 0; kt < 4; ++kt) {
                bf16x8 h0a = ld16(&sA[rb][l16 * H0STR + kt * 32 + quad * 8]);
#pragma unroll
                for (int g = 0; g < 4; ++g)
                    a[g] = __builtin_amdgcn_mfma_f32_16x16x32_bf16(
                        h0a, wi1f[g][kt], a[g], 0, 0, 0);
            }
#pragma unroll
            for (int kt = 0; kt < 4; ++kt) {
                bf16x8 hb = ld16(&sB[rb][l16 * H1STR + kt * 32 + quad * 8]);
#pragma unroll
                for (int g = 0; g < 4; ++g)
                    a[g] = __builtin_amdgcn_mfma_f32_16x16x32_bf16(
                        hb, wh1f[g][kt], a[g], 0, 0, 0);
            }
#pragma unroll
            for (int r = 0; r < 4; ++r) {
                float iv = sigf(a[0][r]), fv = sigf(a[1][r]);
                float gv = tanhf_(a[2][r]), ov = sigf(a[3][r]);
                float cv = fv * c1[r] + iv * gv;
                c1[r] = cv;
                sB[wb][(quad * 4 + r) * H1STR + w * 16 + l16] = f2b(ov * tanhf_(cv));
            }
            if (hn) {
                int row = tid >> 5, col4 = (tid & 31) * 4;
                *(uint2*)&sA[wb][row * H0STR + col4] = pf;
            }
            __syncthreads();
        }

        // h1(T-1) is in sB[0]  (t=511: wb=0)
        if (tid < 256) {
            int m = tid >> 4, j0 = (tid & 15) * 4;
            float s0 = ldf(cb1, j0, m32), s1 = ldf(cb1, j0 + 1, m32);
            float s2 = ldf(cb1, j0 + 2, m32), s3 = ldf(cb1, j0 + 3, m32);
            const ushort* hr = &sB[0][m * H1STR];
#pragma unroll 4
            for (int k = 0; k < 128; ++k) {
                float hv = b2f(hr[k]);
                s0 += hv * ldf(cw1, (long)j0 * 128 + k, m32);
                s1 += hv * ldf(cw1, (long)(j0 + 1) * 128 + k, m32);
                s2 += hv * ldf(cw1, (long)(j0 + 2) * 128 + k, m32);
                s3 += hv * ldf(cw1, (long)(j0 + 3) * 128 + k, m32);
            }
            rs[m * 64 + j0]     = fmaxf(s0, 0.f);
            rs[m * 64 + j0 + 1] = fmaxf(s1, 0.f);
            rs[m * 64 + j0 + 2] = fmaxf(s2, 0.f);
            rs[m * 64 + j0 + 3] = fmaxf(s3, 0.f);
        }
        __syncthreads();
        if (tid < 160) {
            int m = tid / 10, cc = tid - m * 10;
            float s = ldf(cb2, cc, m32);
#pragma unroll
            for (int j = 0; j < 64; ++j)
                s += rs[m * 64 + j] * ldf(cw2, (long)cc * 64 + j, m32);
            long oi = (long)(bt0 + m) * C_ + cc;
            if (m32) ((float*)out)[oi] = s; else ((ushort*)out)[oi] = f2b(s);
        }
        for (int idx = tid; idx < BT * H_; idx += BLK) {
            int m = idx >> 7, k = idx & 127;
            float v = b2f(sB[0][m * H1STR + k]);
            long oi = (long)B_ * C_ + (long)(bt0 + m) * H_ + k;
            if (m32) ((float*)out)[oi] = v; else ((ushort*)out)[oi] = f2b(v);
        }
    }
}

// =====================================================================
// Fallback: proven R5 monolithic kernel (used when ws too small for FIFO)
// =====================================================================
__global__ __launch_bounds__(BLK, 2) void lstm2_mono(
    const void* __restrict__ x,
    const void* __restrict__ wih0, const void* __restrict__ whh0,
    const void* __restrict__ bih0, const void* __restrict__ bhh0,
    const void* __restrict__ wih1, const void* __restrict__ whh1,
    const void* __restrict__ bih1, const void* __restrict__ bhh1,
    const void* __restrict__ cw1, const void* __restrict__ cb1,
    const void* __restrict__ cw2, const void* __restrict__ cb2,
    const int* __restrict__ flag, void* __restrict__ out)
{
    __shared__ __align__(16) ushort h0s[2][BT * H0STR];
    __shared__ __align__(16) ushort h1s[2][BT * H1STR];
    __shared__ float rs[BT * 64];
    __shared__ uint4 xstash[4 * 8 * 64];

    const bool m32 = (*flag) != 0;
    const int tid  = threadIdx.x;
    const int w    = tid >> 6;
    const int lane = tid & 63;
    const int quad = lane >> 4;
    const int l16  = lane & 15;
    const int bt0  = blockIdx.x * BT;

    for (int i = tid; i < BT * 32; i += BLK) {
        int row = i >> 5, cc = i & 31;
        ushort v0 = (cc < 5) ? f2b(ldf(x, ((long)(bt0 + row) * T_) * D_ + cc, m32)) : (ushort)0;
        h0s[0][row * H0STR + 128 + cc] = v0;
        h0s[1][row * H0STR + 128 + cc] = 0;
    }
    for (int i = tid; i < BT * H_; i += BLK) {
        int row = i >> 7, cc = i & 127;
        h1s[1][row * H1STR + cc] = 0;
    }

    bf16x8 wh0c[4][4], wi1f[4][4], wh1f[4][4];
    float  b0v[4], b1v[4];
#pragma unroll
    for (int g = 0; g < 4; ++g) {
        const int n = g * 128 + w * 16 + l16;
#pragma unroll
        for (int kt = 0; kt < 4; ++kt) {
            wh0c[g][kt] = ldfrag(whh0, (long)n * 128 + kt * 32 + quad * 8, m32);
            wi1f[g][kt] = ldfrag(wih1, (long)n * 128 + kt * 32 + quad * 8, m32);
            wh1f[g][kt] = ldfrag(whh1, (long)n * 128 + kt * 32 + quad * 8, m32);
        }
        union { ushort u[8]; uint4 q; } xt;
        xt.q = make_uint4(0, 0, 0, 0);
        if (quad == 0) {
#pragma unroll
            for (int j = 0; j < 5; ++j) xt.u[j] = f2b(ldf(wih0, (long)n * D_ + j, m32));
        }
        xstash[(g * 8 + w) * 64 + lane] = xt.q;
        b0v[g] = ldf(bih0, n, m32) + ldf(bhh0, n, m32);
        b1v[g] = ldf(bih1, n, m32) + ldf(bhh1, n, m32);
    }
    __syncthreads();

    bf16x8 h0f[4];
    {
        uint4 z = make_uint4(0, 0, 0, 0);
        h0f[0] = h0f[1] = h0f[2] = h0f[3] = __builtin_bit_cast(bf16x8, z);
    }
    f32x4 c0 = splat4(0.f), c1 = splat4(0.f);
    const int xr = tid / 5, xc = tid - (tid / 5) * 5;

#pragma unroll 1
    for (int t = 0; t < T_; ++t) {
        const int wb = (t + 1) & 1, rb = t & 1;
        float xv = 0.f;
        const bool stage = (tid < 80) && (t < T_ - 1);
        if (stage) xv = ldf(x, ((long)(bt0 + xr) * T_ + (t + 1)) * D_ + xc, m32);

        f32x4 a[4];
#pragma unroll
        for (int g = 0; g < 4; ++g) a[g] = splat4(b0v[g]);
#pragma unroll
        for (int kt = 0; kt < 4; ++kt)
#pragma unroll
            for (int g = 0; g < 4; ++g)
                a[g] = __builtin_amdgcn_mfma_f32_16x16x32_bf16(
                    h0f[kt], wh0c[g][kt], a[g], 0, 0, 0);
        {
            bf16x8 ha4 = ld16(&h0s[rb][l16 * H0STR + 128 + quad * 8]);
#pragma unroll
            for (int g = 0; g < 4; ++g) {
                bf16x8 xb = __builtin_bit_cast(bf16x8, xstash[(g * 8 + w) * 64 + lane]);
                a[g] = __builtin_amdgcn_mfma_f32_16x16x32_bf16(ha4, xb, a[g], 0, 0, 0);
            }
        }
        ushort h0w[4];
#pragma unroll
        for (int r = 0; r < 4; ++r) {
            float iv = sigf(a[0][r]), fv = sigf(a[1][r]);
            float gv = tanhf_(a[2][r]), ov = sigf(a[3][r]);
            float cv = fv * c0[r] + iv * gv;
            c0[r] = cv;
            h0w[r] = f2b(ov * tanhf_(cv));
        }
#pragma unroll
        for (int r = 0; r < 4; ++r)
            h0s[wb][(quad * 4 + r) * H0STR + w * 16 + l16] = h0w[r];
        if (stage) h0s[wb][xr * H0STR + 128 + xc] = f2b(xv);
        __syncthreads();
#pragma unroll
        for (int kt = 0; kt < 4; ++kt)
            h0f[kt] = ld16(&h0s[wb][l16 * H0STR + kt * 32 + quad * 8]);

#pragma unroll
        for (int g = 0; g < 4; ++g) a[g] = splat4(b1v[g]);
#pragma unroll
        for (int kt = 0; kt < 4; ++kt)
#pragma unroll
            for (int g = 0; g < 4; ++g)
                a[g] = __builtin_amdgcn_mfma_f32_16x16x32_bf16(
                    h0f[kt], wi1f[g][kt], a[g], 0, 0, 0);
#pragma unroll
        for (int kt = 0; kt < 4; ++kt) {
            bf16x8 hb = ld16(&h1s[wb][l16 * H1STR + kt * 32 + quad * 8]);
#pragma unroll
            for (int g = 0; g < 4; ++g)
                a[g] = __builtin_amdgcn_mfma_f32_16x16x32_bf16(
                    hb, wh1f[g][kt], a[g], 0, 0, 0);
        }
#pragma unroll
        for (int r = 0; r < 4; ++r) {
            float iv = sigf(a[0][r]), fv = sigf(a[1][r]);
            float gv = tanhf_(a[2][r]), ov = sigf(a[3][r]);
            float cv = fv * c1[r] + iv * gv;
            c1[r] = cv;
            h1s[wb ^ 1][(quad * 4 + r) * H1STR + w * 16 + l16] = f2b(ov * tanhf_(cv));
        }
    }
    __syncthreads();

    if (tid < 256) {
        int m = tid >> 4, j0 = (tid & 15) * 4;
        float s0 = ldf(cb1, j0, m32), s1 = ldf(cb1, j0 + 1, m32);
        float s2 = ldf(cb1, j0 + 2, m32), s3 = ldf(cb1, j0 + 3, m32);
        const ushort* hr = &h1s[1][m * H1STR];
#pragma unroll 4
        for (int k = 0; k < 128; ++k) {
            float hv = b2f(hr[k]);
            s0 += hv * ldf(cw1, (long)j0 * 128 + k, m32);
            s1 += hv * ldf(cw1, (long)(j0 + 1) * 128 + k, m32);
            s2 += hv * ldf(cw1, (long)(j0 + 2) * 128 + k, m32);
            s3 += hv * ldf(cw1, (long)(j0 + 3) * 128 + k, m32);
        }
        rs[m * 64 + j0]     = fmaxf(s0, 0.f);
        rs[m * 64 + j0 + 1] = fmaxf(s1, 0.f);
        rs[m * 64 + j0 + 2] = fmaxf(s2, 0.f);
        rs[m * 64 + j0 + 3] = fmaxf(s3, 0.f);
    }
    __syncthreads();
    if (tid < 160) {
        int m = tid / 10, cc = tid - m * 10;
        float s = ldf(cb2, cc, m32);
#pragma unroll
        for (int j = 0; j < 64; ++j) s += rs[m * 64 + j] * ldf(cw2, (long)cc * 64 + j, m32);
        long oi = (long)(bt0 + m) * C_ + cc;
        if (m32) ((float*)out)[oi] = s; else ((ushort*)out)[oi] = f2b(s);
    }
    for (int idx = tid; idx < BT * H_; idx += BLK) {
        int m = idx >> 7, k = idx & 127;
        float v = b2f(h1s[1][m * H1STR + k]);
        long oi = (long)B_ * C_ + (long)(bt0 + m) * H_ + k;
        if (m32) ((float*)out)[oi] = v; else ((ushort*)out)[oi] = f2b(v);
    }
}

extern "C" void kernel_launch(void* const* d_in, const int* in_sizes, int n_in,
                              void* d_out, int out_size, void* d_ws, size_t ws_size,
                              hipStream_t stream) {
    (void)in_sizes; (void)n_in; (void)out_size;
    int* prog  = (int*)d_ws;                       // prog_p[128] | prog_c[128]
    int* flag  = (int*)((char*)d_ws + 4096);
    ushort* fifo = (ushort*)((char*)d_ws + 8192);

    hipLaunchKernelGGL(detect_dtype, dim3(1), dim3(256), 0, stream,
                       (const ushort*)d_in[2], flag);

    const size_t slot = (size_t)NP * BT * H_ * sizeof(ushort); // all pairs, 1 step
    int F = 0;
    if (ws_size >= 8192 + 64 * slot) F = 64;
    else if (ws_size >= 8192 + 32 * slot) F = 32;

    if (F) {
        hipLaunchKernelGGL(init_flags, dim3(1), dim3(256), 0, stream, prog);
        hipLaunchKernelGGL(lstm2_pipe, dim3(2 * NP), dim3(BLK), 0, stream,
                           d_in[0], d_in[1], d_in[2], d_in[3], d_in[4],
                           d_in[5], d_in[6], d_in[7], d_in[8],
                           d_in[9], d_in[10], d_in[11], d_in[12],
                           (const int*)flag, fifo, prog, prog + NP, F, d_out);
    } else {
        hipLaunchKernelGGL(lstm2_mono, dim3(B_ / BT), dim3(BLK), 0, stream,
                           d_in[0], d_in[1], d_in[2], d_in[3], d_in[4],
                           d_in[5], d_in[6], d_in[7], d_in[8],
                           d_in[9], d_in[10], d_in[11], d_in[12],
                           (const int*)flag, d_out);
    }
}